// Round 7
// baseline (279.652 us; speedup 1.0000x reference)
//
#include <hip/hip_runtime.h>
#include <stdint.h>

typedef unsigned short u16;
typedef unsigned long long u64;
using short8 = __attribute__((ext_vector_type(8))) short;
using f32x16 = __attribute__((ext_vector_type(16))) float;

#define NROWS 65536
#define DIM   512
#define KC    1024

__device__ __forceinline__ u16 f2bf(float f) {  // RNE float->bf16 bits
  unsigned u = __float_as_uint(f);
  return (u16)((u + 0x7fffu + ((u >> 16) & 1u)) >> 16);
}

// ---- W prep: write W^T in MFMA-B-fragment order + ||w||^2 + zero misc -----
// Fragment g (kc*32+p) = 1 KB: lane (h*32+r) holds W[kc*32+r][16p+8h .. +8).
__global__ __launch_bounds__(256) void wprep_kernel(const float* __restrict__ W,
                                                    short8* __restrict__ WhT8,
                                                    float* __restrict__ wnorm,
                                                    int* __restrict__ counts,
                                                    double* __restrict__ sums) {
  if (blockIdx.x == 0) {
    for (int k = threadIdx.x; k < KC; k += 256) counts[k] = 0;
    if (threadIdx.x < 2) sums[threadIdx.x] = 0.0;
  }
  int code = blockIdx.x * 4 + (threadIdx.x >> 6);
  int l = threadIdx.x & 63;
  const float* wr = W + (size_t)code * DIM + l * 8;
  float s = 0.f;
  float4 v0 = *(const float4*)wr;
  float4 v1 = *(const float4*)(wr + 4);
  s = v0.x * v0.x + v0.y * v0.y + v0.z * v0.z + v0.w * v0.w
    + v1.x * v1.x + v1.y * v1.y + v1.z * v1.z + v1.w * v1.w;
  short8 pk;
  pk[0] = (short)f2bf(v0.x); pk[1] = (short)f2bf(v0.y);
  pk[2] = (short)f2bf(v0.z); pk[3] = (short)f2bf(v0.w);
  pk[4] = (short)f2bf(v1.x); pk[5] = (short)f2bf(v1.y);
  pk[6] = (short)f2bf(v1.z); pk[7] = (short)f2bf(v1.w);
  // frag p = l>>1, half h = l&1, col r = code&31, tile kc = code>>5
  WhT8[(size_t)(code >> 5) * 2048 + (l >> 1) * 64 + (l & 1) * 32 + (code & 31)] = pk;
#pragma unroll
  for (int off = 32; off; off >>= 1) s += __shfl_xor(s, off, 64);
  if (l == 0) wnorm[code] = s;
}

// ---- main fused kernel: A-in-regs, B streamed L2->register ring -----------
// 256 thr = 4 waves, 2 blocks/CU, block = 128 rows, wave = 32 rows.
// No LDS, no barriers in the K-loop. Fused argmin/hist/sums/quant/one-hot.
__global__ __launch_bounds__(256, 2) void mm_kernel(
    const float* __restrict__ X, const float* __restrict__ W,
    const short8* __restrict__ WhT8, const float* __restrict__ wnorm,
    int* __restrict__ counts, double* __restrict__ sums,
    float* __restrict__ quant, float* __restrict__ encf) {
  __shared__ int rowk[128];
  __shared__ double sdbl[4];
  const int t = threadIdx.x;
  const int w = t >> 6, l = t & 63;
  const int r = l & 31, h = l >> 5;
  const int row0 = blockIdx.x * 128;

  // A panel (32 rows x 512) -> registers as MFMA A-frags, fused sum(x^2)
  const float* Xr = X + (size_t)(row0 + w * 32 + r) * DIM + h * 8;
  short8 aF[32];
  double xacc = 0.0;
#pragma unroll
  for (int s = 0; s < 32; ++s) {
    float4 v0 = *(const float4*)(Xr + s * 16);
    float4 v1 = *(const float4*)(Xr + s * 16 + 4);
    xacc += (double)v0.x * v0.x + (double)v0.y * v0.y + (double)v0.z * v0.z + (double)v0.w * v0.w
          + (double)v1.x * v1.x + (double)v1.y * v1.y + (double)v1.z * v1.z + (double)v1.w * v1.w;
    short8 pk;
    pk[0] = (short)f2bf(v0.x); pk[1] = (short)f2bf(v0.y);
    pk[2] = (short)f2bf(v0.z); pk[3] = (short)f2bf(v0.w);
    pk[4] = (short)f2bf(v1.x); pk[5] = (short)f2bf(v1.y);
    pk[6] = (short)f2bf(v1.z); pk[7] = (short)f2bf(v1.w);
    aF[s] = pk;
  }
#pragma unroll
  for (int off = 32; off; off >>= 1) xacc += __shfl_xor(xacc, off, 64);
  if (l == 0) atomicAdd(&sums[0], xacc);

  // B-fragment register ring, depth 8 (covers L2 latency under 8 MFMAs)
  short8 ring[8];
#pragma unroll
  for (int i = 0; i < 8; ++i) ring[i] = WhT8[(size_t)i * 64 + l];

  u64 best_[16];
#pragma unroll
  for (int q = 0; q < 16; ++q) best_[q] = ~0ull;

  float4* encz = (float4*)(encf + (size_t)row0 * KC);
  const float4 zero4 = {0.f, 0.f, 0.f, 0.f};

  for (int kc = 0; kc < 32; ++kc) {
    // stream this block's one-hot zeros (1/32 per tile, hides under MFMA)
#pragma unroll
    for (int j = 0; j < 4; ++j) encz[kc * 1024 + j * 256 + t] = zero4;
    f32x16 acc = {};
#pragma unroll
    for (int ph = 0; ph < 32; ++ph) {
      const int g = kc * 32 + ph;
      acc = __builtin_amdgcn_mfma_f32_32x32x16_bf16(aF[ph], ring[ph & 7], acc, 0, 0, 0);
      if (g + 8 < 1024) ring[ph & 7] = WhT8[(size_t)(g + 8) * 64 + l];
    }
    float wn = wnorm[kc * 32 + r];
    unsigned col = (unsigned)(kc * 32 + r);
#pragma unroll
    for (int q = 0; q < 16; ++q) {
      float sc = fmaf(-2.0f, acc[q], wn);
      unsigned u_ = __float_as_uint(sc);
      unsigned key = (u_ & 0x80000000u) ? ~u_ : (u_ | 0x80000000u);
      u64 p_ = ((u64)key << 32) | col;
      if (p_ < best_[q]) best_[q] = p_;
    }
  }

  // per-row argmin across the 32 code-lanes; outputs
  double local = 0.0;
#pragma unroll
  for (int q = 0; q < 16; ++q) {
    u64 pb = best_[q];
#pragma unroll
    for (int off = 16; off; off >>= 1) {
      u64 o = __shfl_xor(pb, off, 32);
      if (o < pb) pb = o;
    }
    if (r == 0) {
      int rit = w * 32 + (q & 3) + 8 * (q >> 2) + 4 * h;
      int k = (int)(pb & 0xffffffffu);
      rowk[rit] = k;
      atomicAdd(&counts[k], 1);
      unsigned key = (unsigned)(pb >> 32);
      unsigned uu = (key & 0x80000000u) ? (key ^ 0x80000000u) : ~key;
      local += (double)__uint_as_float(uu);
    }
  }
  {
    double o32 = __shfl(local, 32, 64);
    if (l == 0) sdbl[w] = local + o32;
  }
  __syncthreads();
  if (t == 0) atomicAdd(&sums[1], sdbl[0] + sdbl[1] + sdbl[2] + sdbl[3]);

  // fused quantized gather-write + one-hot 1.0 scatter
  for (int j = 0; j < 32; ++j) {
    int rit = w * 32 + j;
    int k = rowk[rit];
    size_t row = (size_t)(row0 + rit);
    float4 wv0 = *(const float4*)&W[(size_t)k * DIM + l * 8];
    float4 wv1 = *(const float4*)&W[(size_t)k * DIM + l * 8 + 4];
    float* dst = quant + row * DIM + l * 8;
    dst[0] = wv0.x; dst[1] = wv0.y; dst[2] = wv0.z; dst[3] = wv0.w;
    dst[4] = wv1.x; dst[5] = wv1.y; dst[6] = wv1.z; dst[7] = wv1.w;
    if (l == 0) encf[row * KC + k] = 1.0f;
  }
}

// ---- finalize: loss + perplexity ------------------------------------------
__global__ __launch_bounds__(256) void finalize_kernel(
    const int* __restrict__ counts, const double* __restrict__ sums,
    float* __restrict__ out_loss, float* __restrict__ out_perp) {
  __shared__ float red[4];
  int t = threadIdx.x;
  float h = 0.f;
  for (int k = t; k < KC; k += 256) {
    float p = (float)counts[k] / (float)NROWS;
    h -= p * logf(p + 1e-10f);
  }
#pragma unroll
  for (int off = 32; off; off >>= 1) h += __shfl_xor(h, off, 64);
  if ((t & 63) == 0) red[t >> 6] = h;
  __syncthreads();
  if (t == 0) {
    float H = red[0] + red[1] + red[2] + red[3];
    *out_perp = expf(H);
    double m = (sums[0] + sums[1]) / (double)((long long)NROWS * DIM);
    *out_loss = (float)(1.25 * m);
  }
}

extern "C" void kernel_launch(void* const* d_in, const int* in_sizes, int n_in,
                              void* d_out, int out_size, void* d_ws, size_t ws_size,
                              hipStream_t stream) {
  const float* X = (const float*)d_in[0];
  const float* W = (const float*)d_in[1];
  float* out = (float*)d_out;
  char* ws = (char*)d_ws;

  float* out_loss = out;                     // [0]
  float* quant    = out + 1;                 // [1 .. 1+N*D)
  float* out_perp = out + 1 + NROWS * DIM;   // [33554433]
  float* encf     = out + 2 + NROWS * DIM;   // [33554434 ..), 16B-aligned

  short8* WhT8   = (short8*)ws;                       // 1 MB
  float*  wnorm  = (float*)(ws + (1u << 20));         // 4 KB
  int*    counts = (int*)(ws + (1u << 20) + 4096);    // 4 KB
  double* sums   = (double*)(ws + (1u << 20) + 8192); // [0]=sumX2 [1]=sumS

  wprep_kernel<<<KC / 4, 256, 0, stream>>>(W, WhT8, wnorm, counts, sums);
  mm_kernel<<<NROWS / 128, 256, 0, stream>>>(X, W, WhT8, wnorm, counts, sums,
                                             quant, encf);
  finalize_kernel<<<1, 256, 0, stream>>>(counts, sums, out_loss, out_perp);
}

// Round 8
// 272.826 us; speedup vs baseline: 1.0250x; 1.0250x over previous
//
#include <hip/hip_runtime.h>
#include <stdint.h>

typedef unsigned short u16;
typedef unsigned long long u64;
using short8 = __attribute__((ext_vector_type(8))) short;
using f32x16 = __attribute__((ext_vector_type(16))) float;

#define NROWS 65536
#define DIM   512
#define KC    1024

__device__ __forceinline__ u16 f2bf(float f) {  // RNE float->bf16 bits
  unsigned u = __float_as_uint(f);
  return (u16)((u + 0x7fffu + ((u >> 16) & 1u)) >> 16);
}

// ---- W prep: write W^T in MFMA-B-fragment order + ||w||^2 + zero misc -----
// Fragment g (kc*32+p) = 1 KB: lane (h*32+r) holds W[kc*32+r][16p+8h .. +8).
__global__ __launch_bounds__(256) void wprep_kernel(const float* __restrict__ W,
                                                    short8* __restrict__ WhT8,
                                                    float* __restrict__ wnorm,
                                                    int* __restrict__ counts,
                                                    double* __restrict__ sums) {
  if (blockIdx.x == 0) {
    for (int k = threadIdx.x; k < KC; k += 256) counts[k] = 0;
    if (threadIdx.x < 2) sums[threadIdx.x] = 0.0;
  }
  int code = blockIdx.x * 4 + (threadIdx.x >> 6);
  int l = threadIdx.x & 63;
  const float* wr = W + (size_t)code * DIM + l * 8;
  float s = 0.f;
  float4 v0 = *(const float4*)wr;
  float4 v1 = *(const float4*)(wr + 4);
  s = v0.x * v0.x + v0.y * v0.y + v0.z * v0.z + v0.w * v0.w
    + v1.x * v1.x + v1.y * v1.y + v1.z * v1.z + v1.w * v1.w;
  short8 pk;
  pk[0] = (short)f2bf(v0.x); pk[1] = (short)f2bf(v0.y);
  pk[2] = (short)f2bf(v0.z); pk[3] = (short)f2bf(v0.w);
  pk[4] = (short)f2bf(v1.x); pk[5] = (short)f2bf(v1.y);
  pk[6] = (short)f2bf(v1.z); pk[7] = (short)f2bf(v1.w);
  // frag p = l>>1, half h = l&1, col r = code&31, tile kc = code>>5
  WhT8[(size_t)(code >> 5) * 2048 + (l >> 1) * 64 + (l & 1) * 32 + (code & 31)] = pk;
#pragma unroll
  for (int off = 32; off; off >>= 1) s += __shfl_xor(s, off, 64);
  if (l == 0) wnorm[code] = s;
}

// ---- main fused kernel: A-in-regs, B streamed L2->register ring -----------
// 256 thr = 4 waves, pinned 2 waves/EU (2 blocks/CU, 256-VGPR budget).
// Even/odd-K accumulator chains (2 independent MFMA chains per wave).
// best packed u32: (22-bit monotone score key | 10-bit col), min-fold.
__global__ __launch_bounds__(256)
__attribute__((amdgpu_waves_per_eu(2, 2))) void mm_kernel(
    const float* __restrict__ X, const float* __restrict__ W,
    const short8* __restrict__ WhT8, const float* __restrict__ wnorm,
    int* __restrict__ counts, double* __restrict__ sums,
    float* __restrict__ quant, float* __restrict__ encf) {
  __shared__ int rowk[128];
  __shared__ double sdbl[4];
  const int t = threadIdx.x;
  const int w = t >> 6, l = t & 63;
  const int r = l & 31, h = l >> 5;
  const int row0 = blockIdx.x * 128;

  // A panel (32 rows x 512) -> registers as MFMA A-frags, fused sum(x^2)
  const float* Xr = X + (size_t)(row0 + w * 32 + r) * DIM + h * 8;
  short8 aF[32];
  double xacc = 0.0;
#pragma unroll
  for (int s = 0; s < 32; ++s) {
    float4 v0 = *(const float4*)(Xr + s * 16);
    float4 v1 = *(const float4*)(Xr + s * 16 + 4);
    xacc += (double)v0.x * v0.x + (double)v0.y * v0.y + (double)v0.z * v0.z + (double)v0.w * v0.w
          + (double)v1.x * v1.x + (double)v1.y * v1.y + (double)v1.z * v1.z + (double)v1.w * v1.w;
    short8 pk;
    pk[0] = (short)f2bf(v0.x); pk[1] = (short)f2bf(v0.y);
    pk[2] = (short)f2bf(v0.z); pk[3] = (short)f2bf(v0.w);
    pk[4] = (short)f2bf(v1.x); pk[5] = (short)f2bf(v1.y);
    pk[6] = (short)f2bf(v1.z); pk[7] = (short)f2bf(v1.w);
    aF[s] = pk;
  }
#pragma unroll
  for (int off = 32; off; off >>= 1) xacc += __shfl_xor(xacc, off, 64);
  if (l == 0) atomicAdd(&sums[0], xacc);

  // B-fragment register ring, depth 8 (covers L2 latency under MFMAs)
  short8 ring[8];
#pragma unroll
  for (int i = 0; i < 8; ++i) ring[i] = WhT8[(size_t)i * 64 + l];

  unsigned best_[16];
#pragma unroll
  for (int q = 0; q < 16; ++q) best_[q] = 0xFFFFFFFFu;

  float4* encz = (float4*)(encf + (size_t)row0 * KC);
  const float4 zero4 = {0.f, 0.f, 0.f, 0.f};

  for (int kc = 0; kc < 32; ++kc) {
    // stream this block's one-hot zeros (1/32 per tile, hides under MFMA)
#pragma unroll
    for (int j = 0; j < 4; ++j) encz[kc * 1024 + j * 256 + t] = zero4;
    f32x16 acc_e = {}, acc_o = {};
#pragma unroll
    for (int ph = 0; ph < 32; ++ph) {
      const int g = kc * 32 + ph;
      if (ph & 1)
        acc_o = __builtin_amdgcn_mfma_f32_32x32x16_bf16(aF[ph], ring[ph & 7], acc_o, 0, 0, 0);
      else
        acc_e = __builtin_amdgcn_mfma_f32_32x32x16_bf16(aF[ph], ring[ph & 7], acc_e, 0, 0, 0);
      ring[ph & 7] = WhT8[(size_t)(g + 8) * 64 + l];  // WhT8 padded by 8 frags
    }
    float wn = wnorm[kc * 32 + r];
    unsigned col = (unsigned)(kc * 32 + r);
#pragma unroll
    for (int q = 0; q < 16; ++q) {
      float sc = fmaf(-2.0f, acc_e[q] + acc_o[q], wn);
      unsigned u_ = __float_as_uint(sc);
      unsigned key = (u_ & 0x80000000u) ? ~u_ : (u_ | 0x80000000u);
      unsigned kk = (key & 0xFFFFFC00u) | col;
      best_[q] = min(best_[q], kk);
    }
  }

  // per-row argmin across the 32 code-lanes; outputs
  double local = 0.0;
#pragma unroll
  for (int q = 0; q < 16; ++q) {
    unsigned pb = best_[q];
#pragma unroll
    for (int off = 16; off; off >>= 1)
      pb = min(pb, (unsigned)__shfl_xor((int)pb, off, 32));
    if (r == 0) {
      int rit = w * 32 + (q & 3) + 8 * (q >> 2) + 4 * h;
      int k = (int)(pb & 1023u);
      rowk[rit] = k;
      atomicAdd(&counts[k], 1);
      unsigned key = (pb & 0xFFFFFC00u) | 0x200u;  // midpoint reconstruction
      unsigned uu = (key & 0x80000000u) ? (key ^ 0x80000000u) : ~key;
      local += (double)__uint_as_float(uu);
    }
  }
  {
    double o32 = __shfl(local, 32, 64);
    if (l == 0) sdbl[w] = local + o32;
  }
  __syncthreads();
  if (t == 0) atomicAdd(&sums[1], sdbl[0] + sdbl[1] + sdbl[2] + sdbl[3]);

  // fused quantized gather-write + one-hot 1.0 scatter
  for (int j = 0; j < 32; ++j) {
    int rit = w * 32 + j;
    int k = rowk[rit];
    size_t row = (size_t)(row0 + rit);
    float4 wv0 = *(const float4*)&W[(size_t)k * DIM + l * 8];
    float4 wv1 = *(const float4*)&W[(size_t)k * DIM + l * 8 + 4];
    float* dst = quant + row * DIM + l * 8;
    dst[0] = wv0.x; dst[1] = wv0.y; dst[2] = wv0.z; dst[3] = wv0.w;
    dst[4] = wv1.x; dst[5] = wv1.y; dst[6] = wv1.z; dst[7] = wv1.w;
    if (l == 0) encf[row * KC + k] = 1.0f;
  }
}

// ---- finalize: loss + perplexity ------------------------------------------
__global__ __launch_bounds__(256) void finalize_kernel(
    const int* __restrict__ counts, const double* __restrict__ sums,
    float* __restrict__ out_loss, float* __restrict__ out_perp) {
  __shared__ float red[4];
  int t = threadIdx.x;
  float h = 0.f;
  for (int k = t; k < KC; k += 256) {
    float p = (float)counts[k] / (float)NROWS;
    h -= p * logf(p + 1e-10f);
  }
#pragma unroll
  for (int off = 32; off; off >>= 1) h += __shfl_xor(h, off, 64);
  if ((t & 63) == 0) red[t >> 6] = h;
  __syncthreads();
  if (t == 0) {
    float H = red[0] + red[1] + red[2] + red[3];
    *out_perp = expf(H);
    double m = (sums[0] + sums[1]) / (double)((long long)NROWS * DIM);
    *out_loss = (float)(1.25 * m);
  }
}

extern "C" void kernel_launch(void* const* d_in, const int* in_sizes, int n_in,
                              void* d_out, int out_size, void* d_ws, size_t ws_size,
                              hipStream_t stream) {
  const float* X = (const float*)d_in[0];
  const float* W = (const float*)d_in[1];
  float* out = (float*)d_out;
  char* ws = (char*)d_ws;

  float* out_loss = out;                     // [0]
  float* quant    = out + 1;                 // [1 .. 1+N*D)
  float* out_perp = out + 1 + NROWS * DIM;   // [33554433]
  float* encf     = out + 2 + NROWS * DIM;   // [33554434 ..), 16B-aligned

  short8* WhT8   = (short8*)ws;                       // 1 MB + 8 KB pad
  float*  wnorm  = (float*)(ws + (1056u << 10));      // 4 KB
  int*    counts = (int*)(ws + (1056u << 10) + 4096); // 4 KB
  double* sums   = (double*)(ws + (1056u << 10) + 8192); // [0]=sumX2 [1]=sumS

  wprep_kernel<<<KC / 4, 256, 0, stream>>>(W, WhT8, wnorm, counts, sums);
  mm_kernel<<<NROWS / 128, 256, 0, stream>>>(X, W, WhT8, wnorm, counts, sums,
                                             quant, encf);
  finalize_kernel<<<1, 256, 0, stream>>>(counts, sums, out_loss, out_perp);
}

// Round 9
// 193.201 us; speedup vs baseline: 1.4475x; 1.4121x over previous
//
#include <hip/hip_runtime.h>
#include <stdint.h>

typedef unsigned short u16;
typedef unsigned long long u64;
using short8 = __attribute__((ext_vector_type(8))) short;
using f32x16 = __attribute__((ext_vector_type(16))) float;

#define NROWS 65536
#define DIM   512
#define KC    1024

#define GLOBAL_AS __attribute__((address_space(1)))
#define LDS_AS    __attribute__((address_space(3)))

__device__ __forceinline__ void gload_lds16(const void* g, void* l) {
  __builtin_amdgcn_global_load_lds((const GLOBAL_AS uint32_t*)g,
                                   (LDS_AS uint32_t*)l, 16, 0, 0);
}

__device__ __forceinline__ u16 f2bf(float f) {  // RNE float->bf16 bits
  unsigned u = __float_as_uint(f);
  return (u16)((u + 0x7fffu + ((u >> 16) & 1u)) >> 16);
}

// ---- W prep: W^T in MFMA-B-fragment order (32-code tiles) + ||w||^2 -------
// Tile kt (32 codes) = 32 KB; frag ks = 1 KB, lane-contiguous:
// lane (h*32+r) holds W[kt*32+r][ks*16+8h .. +8).
__global__ __launch_bounds__(256) void wprep_kernel(const float* __restrict__ W,
                                                    short8* __restrict__ WhT8,
                                                    float* __restrict__ wnorm,
                                                    int* __restrict__ counts,
                                                    double* __restrict__ sums) {
  if (blockIdx.x == 0) {
    for (int k = threadIdx.x; k < KC; k += 256) counts[k] = 0;
    if (threadIdx.x < 2) sums[threadIdx.x] = 0.0;
  }
  int code = blockIdx.x * 4 + (threadIdx.x >> 6);
  int l = threadIdx.x & 63;
  const float* wr = W + (size_t)code * DIM + l * 8;
  float4 v0 = *(const float4*)wr;
  float4 v1 = *(const float4*)(wr + 4);
  float s = v0.x * v0.x + v0.y * v0.y + v0.z * v0.z + v0.w * v0.w
          + v1.x * v1.x + v1.y * v1.y + v1.z * v1.z + v1.w * v1.w;
  short8 pk;
  pk[0] = (short)f2bf(v0.x); pk[1] = (short)f2bf(v0.y);
  pk[2] = (short)f2bf(v0.z); pk[3] = (short)f2bf(v0.w);
  pk[4] = (short)f2bf(v1.x); pk[5] = (short)f2bf(v1.y);
  pk[6] = (short)f2bf(v1.z); pk[7] = (short)f2bf(v1.w);
  // frag ks = l>>1, half = l&1, col = code&31, tile = code>>5
  WhT8[(size_t)(code >> 5) * 2048 + (l >> 1) * 64 + (l & 1) * 32 + (code & 31)] = pk;
#pragma unroll
  for (int off = 32; off; off >>= 1) s += __shfl_xor(s, off, 64);
  if (l == 0) wnorm[code] = s;
}

// ---- main fused kernel ----------------------------------------------------
// 256 thr = 4 waves x 32 rows = 128 rows/block, grid 512 = 2 blocks/CU.
// A (32x512) in regs per wave; B streams 32-code (32 KB) tiles through
// double-buffered LDS via linear global_load_lds from fragment-ordered WhT.
// ds_read: frag ks at buf + ks*1024 + lane*16 -> contiguous, conflict-free,
// compile-time offsets. One barrier per tile; gloads issued issue-early.
__global__ __launch_bounds__(256)
__attribute__((amdgpu_waves_per_eu(2, 2))) void mm_kernel(
    const float* __restrict__ X, const float* __restrict__ W,
    const u16* __restrict__ WhTf, const float* __restrict__ wnorm,
    int* __restrict__ counts, double* __restrict__ sums,
    float* __restrict__ quant, float* __restrict__ encf) {
  __shared__ __align__(16) u16 BsU[2][16384];  // 2 x 32 KB
  __shared__ int rowk[128];
  __shared__ double sdbl[4];
  const int t = threadIdx.x;
  const int w = t >> 6, l = t & 63;
  const int r = l & 31, h = l >> 5;
  const int row0 = blockIdx.x * 128;

  // kick off tile 0 DMA (linear: frag-ordered source, linear LDS dest)
#pragma unroll
  for (int i = 0; i < 8; ++i)
    gload_lds16(WhTf + i * 2048 + t * 8, &BsU[0][i * 2048 + t * 8]);

  // A panel (32 rows x 512) -> registers as MFMA A-frags, fused sum(x^2)
  const float* Xr = X + (size_t)(row0 + w * 32 + r) * DIM + h * 8;
  short8 aF[32];
  double xacc = 0.0;
#pragma unroll
  for (int s = 0; s < 32; ++s) {
    float4 v0 = *(const float4*)(Xr + s * 16);
    float4 v1 = *(const float4*)(Xr + s * 16 + 4);
    xacc += (double)v0.x * v0.x + (double)v0.y * v0.y + (double)v0.z * v0.z + (double)v0.w * v0.w
          + (double)v1.x * v1.x + (double)v1.y * v1.y + (double)v1.z * v1.z + (double)v1.w * v1.w;
    short8 pk;
    pk[0] = (short)f2bf(v0.x); pk[1] = (short)f2bf(v0.y);
    pk[2] = (short)f2bf(v0.z); pk[3] = (short)f2bf(v0.w);
    pk[4] = (short)f2bf(v1.x); pk[5] = (short)f2bf(v1.y);
    pk[6] = (short)f2bf(v1.z); pk[7] = (short)f2bf(v1.w);
    aF[s] = pk;
  }
#pragma unroll
  for (int off = 32; off; off >>= 1) xacc += __shfl_xor(xacc, off, 64);
  if (l == 0) atomicAdd(&sums[0], xacc);

  unsigned best_[16];
#pragma unroll
  for (int q = 0; q < 16; ++q) best_[q] = 0xFFFFFFFFu;

  float4* encz = (float4*)(encf + (size_t)row0 * KC);
  const float4 zero4 = {0.f, 0.f, 0.f, 0.f};

  __syncthreads();  // tile 0 resident (barrier drains vmcnt)

  for (int kt = 0; kt < 32; ++kt) {
    const int buf = kt & 1;
    if (kt < 31) {  // issue-early: next tile DMA before compute
      const u16* src = WhTf + (size_t)(kt + 1) * 16384;
#pragma unroll
      for (int i = 0; i < 8; ++i)
        gload_lds16(src + i * 2048 + t * 8, &BsU[buf ^ 1][i * 2048 + t * 8]);
    }
    // stream one-hot zeros for this block's stripe (16 KB/tile)
#pragma unroll
    for (int j = 0; j < 4; ++j) encz[kt * 1024 + j * 256 + t] = zero4;

    const u16* bufp = &BsU[buf][l * 8];
    f32x16 acc_e = {}, acc_o = {};
#pragma unroll
    for (int ks = 0; ks < 32; ++ks) {
      short8 bv = *(const short8*)&bufp[ks * 512];
      if (ks & 1)
        acc_o = __builtin_amdgcn_mfma_f32_32x32x16_bf16(aF[ks], bv, acc_o, 0, 0, 0);
      else
        acc_e = __builtin_amdgcn_mfma_f32_32x32x16_bf16(aF[ks], bv, acc_e, 0, 0, 0);
    }
    float wn = wnorm[kt * 32 + r];
    unsigned col = (unsigned)(kt * 32 + r);
#pragma unroll
    for (int q = 0; q < 16; ++q) {
      float sc = fmaf(-2.0f, acc_e[q] + acc_o[q], wn);
      unsigned u_ = __float_as_uint(sc);
      unsigned key = (u_ & 0x80000000u) ? ~u_ : (u_ | 0x80000000u);
      best_[q] = min(best_[q], (key & 0xFFFFFC00u) | col);
    }
    __syncthreads();  // all waves done with buf; next iter overwrites it
  }

  // per-row argmin across the 32 code-lanes; outputs
  double local = 0.0;
#pragma unroll
  for (int q = 0; q < 16; ++q) {
    unsigned pb = best_[q];
#pragma unroll
    for (int off = 16; off; off >>= 1)
      pb = min(pb, (unsigned)__shfl_xor((int)pb, off, 32));
    if (r == 0) {
      int rit = w * 32 + (q & 3) + 8 * (q >> 2) + 4 * h;
      int k = (int)(pb & 1023u);
      rowk[rit] = k;
      atomicAdd(&counts[k], 1);
      unsigned key = (pb & 0xFFFFFC00u) | 0x200u;  // midpoint reconstruction
      unsigned uu = (key & 0x80000000u) ? (key ^ 0x80000000u) : ~key;
      local += (double)__uint_as_float(uu);
    }
  }
  {
    double o32 = __shfl(local, 32, 64);
    if (l == 0) sdbl[w] = local + o32;
  }
  __syncthreads();
  if (t == 0) atomicAdd(&sums[1], sdbl[0] + sdbl[1] + sdbl[2] + sdbl[3]);

  // fused quantized gather-write + one-hot 1.0 scatter
  for (int j = 0; j < 32; ++j) {
    int rit = w * 32 + j;
    int k = rowk[rit];
    size_t row = (size_t)(row0 + rit);
    float4 wv0 = *(const float4*)&W[(size_t)k * DIM + l * 8];
    float4 wv1 = *(const float4*)&W[(size_t)k * DIM + l * 8 + 4];
    float* dst = quant + row * DIM + l * 8;
    dst[0] = wv0.x; dst[1] = wv0.y; dst[2] = wv0.z; dst[3] = wv0.w;
    dst[4] = wv1.x; dst[5] = wv1.y; dst[6] = wv1.z; dst[7] = wv1.w;
    if (l == 0) encf[row * KC + k] = 1.0f;
  }
}

// ---- finalize: loss + perplexity ------------------------------------------
__global__ __launch_bounds__(256) void finalize_kernel(
    const int* __restrict__ counts, const double* __restrict__ sums,
    float* __restrict__ out_loss, float* __restrict__ out_perp) {
  __shared__ float red[4];
  int t = threadIdx.x;
  float h = 0.f;
  for (int k = t; k < KC; k += 256) {
    float p = (float)counts[k] / (float)NROWS;
    h -= p * logf(p + 1e-10f);
  }
#pragma unroll
  for (int off = 32; off; off >>= 1) h += __shfl_xor(h, off, 64);
  if ((t & 63) == 0) red[t >> 6] = h;
  __syncthreads();
  if (t == 0) {
    float H = red[0] + red[1] + red[2] + red[3];
    *out_perp = expf(H);
    double m = (sums[0] + sums[1]) / (double)((long long)NROWS * DIM);
    *out_loss = (float)(1.25 * m);
  }
}

extern "C" void kernel_launch(void* const* d_in, const int* in_sizes, int n_in,
                              void* d_out, int out_size, void* d_ws, size_t ws_size,
                              hipStream_t stream) {
  const float* X = (const float*)d_in[0];
  const float* W = (const float*)d_in[1];
  float* out = (float*)d_out;
  char* ws = (char*)d_ws;

  float* out_loss = out;                     // [0]
  float* quant    = out + 1;                 // [1 .. 1+N*D)
  float* out_perp = out + 1 + NROWS * DIM;   // [33554433]
  float* encf     = out + 2 + NROWS * DIM;   // [33554434 ..), 16B-aligned

  short8* WhT8   = (short8*)ws;                        // 1 MB
  float*  wnorm  = (float*)(ws + (1040u << 10));       // 4 KB
  int*    counts = (int*)(ws + (1040u << 10) + 4096);  // 4 KB
  double* sums   = (double*)(ws + (1040u << 10) + 8192); // [0]=sumX2 [1]=sumS

  wprep_kernel<<<KC / 4, 256, 0, stream>>>(W, WhT8, wnorm, counts, sums);
  mm_kernel<<<NROWS / 128, 256, 0, stream>>>(X, W, (const u16*)WhT8, wnorm,
                                             counts, sums, quant, encf);
  finalize_kernel<<<1, 256, 0, stream>>>(counts, sums, out_loss, out_perp);
}

// Round 10
// 180.354 us; speedup vs baseline: 1.5506x; 1.0712x over previous
//
#include <hip/hip_runtime.h>
#include <stdint.h>

typedef unsigned short u16;
typedef unsigned long long u64;
using short8 = __attribute__((ext_vector_type(8))) short;
using f32x16 = __attribute__((ext_vector_type(16))) float;
using f32x4v = __attribute__((ext_vector_type(4))) float;

#define NROWS 65536
#define DIM   512
#define KC    1024

#define GLOBAL_AS __attribute__((address_space(1)))
#define LDS_AS    __attribute__((address_space(3)))

__device__ __forceinline__ void gload_lds16(const void* g, void* l) {
  __builtin_amdgcn_global_load_lds((const GLOBAL_AS uint32_t*)g,
                                   (LDS_AS uint32_t*)l, 16, 0, 0);
}

__device__ __forceinline__ u16 f2bf(float f) {  // RNE float->bf16 bits
  unsigned u = __float_as_uint(f);
  return (u16)((u + 0x7fffu + ((u >> 16) & 1u)) >> 16);
}

__device__ __forceinline__ f32x4v ntload4(const float* p) {
  return __builtin_nontemporal_load((const f32x4v*)p);
}
__device__ __forceinline__ void ntstore4(float* p, f32x4v v) {
  __builtin_nontemporal_store(v, (f32x4v*)p);
}

// ---- W prep: W^T in MFMA-B-fragment order (32-code tiles) + ||w||^2 -------
__global__ __launch_bounds__(256) void wprep_kernel(const float* __restrict__ W,
                                                    short8* __restrict__ WhT8,
                                                    float* __restrict__ wnorm,
                                                    int* __restrict__ counts,
                                                    double* __restrict__ sums) {
  if (blockIdx.x == 0) {
    for (int k = threadIdx.x; k < KC; k += 256) counts[k] = 0;
    if (threadIdx.x < 2) sums[threadIdx.x] = 0.0;
  }
  int code = blockIdx.x * 4 + (threadIdx.x >> 6);
  int l = threadIdx.x & 63;
  const float* wr = W + (size_t)code * DIM + l * 8;
  float4 v0 = *(const float4*)wr;
  float4 v1 = *(const float4*)(wr + 4);
  float s = v0.x * v0.x + v0.y * v0.y + v0.z * v0.z + v0.w * v0.w
          + v1.x * v1.x + v1.y * v1.y + v1.z * v1.z + v1.w * v1.w;
  short8 pk;
  pk[0] = (short)f2bf(v0.x); pk[1] = (short)f2bf(v0.y);
  pk[2] = (short)f2bf(v0.z); pk[3] = (short)f2bf(v0.w);
  pk[4] = (short)f2bf(v1.x); pk[5] = (short)f2bf(v1.y);
  pk[6] = (short)f2bf(v1.z); pk[7] = (short)f2bf(v1.w);
  WhT8[(size_t)(code >> 5) * 2048 + (l >> 1) * 64 + (l & 1) * 32 + (code & 31)] = pk;
#pragma unroll
  for (int off = 32; off; off >>= 1) s += __shfl_xor(s, off, 64);
  if (l == 0) wnorm[code] = s;
}

// ---- main fused kernel ----------------------------------------------------
// 256 thr = 4 waves x 32 rows; grid 512 = 2 blocks/CU. A in regs; B streams
// 32-code tiles via linear global_load_lds; NT output streams protect L2.
__global__ __launch_bounds__(256)
__attribute__((amdgpu_waves_per_eu(2, 2))) void mm_kernel(
    const float* __restrict__ X, const float* __restrict__ W,
    const u16* __restrict__ WhTf, const float* __restrict__ wnorm,
    int* __restrict__ counts, double* __restrict__ sums,
    float* __restrict__ out, float* __restrict__ encf) {
  __shared__ __align__(16) u16 BsU[2][16384];  // 2 x 32 KB
  __shared__ int rowk[128];
  __shared__ double sdbl[4];
  const int t = threadIdx.x;
  const int w = t >> 6, l = t & 63;
  const int r = l & 31, h = l >> 5;
  const int row0 = blockIdx.x * 128;

  // kick off tile 0 DMA (oldest vmcnt entries; drains during A prologue)
#pragma unroll
  for (int i = 0; i < 8; ++i)
    gload_lds16(WhTf + i * 2048 + t * 8, &BsU[0][i * 2048 + t * 8]);

  // A panel (32 rows x 512) -> regs as MFMA A-frags (NT loads), sum(x^2)
  const float* Xr = X + (size_t)(row0 + w * 32 + r) * DIM + h * 8;
  short8 aF[32];
  double xacc = 0.0;
#pragma unroll
  for (int s = 0; s < 32; ++s) {
    f32x4v v0 = ntload4(Xr + s * 16);
    f32x4v v1 = ntload4(Xr + s * 16 + 4);
    xacc += (double)v0[0] * v0[0] + (double)v0[1] * v0[1] + (double)v0[2] * v0[2] + (double)v0[3] * v0[3]
          + (double)v1[0] * v1[0] + (double)v1[1] * v1[1] + (double)v1[2] * v1[2] + (double)v1[3] * v1[3];
    short8 pk;
    pk[0] = (short)f2bf(v0[0]); pk[1] = (short)f2bf(v0[1]);
    pk[2] = (short)f2bf(v0[2]); pk[3] = (short)f2bf(v0[3]);
    pk[4] = (short)f2bf(v1[0]); pk[5] = (short)f2bf(v1[1]);
    pk[6] = (short)f2bf(v1[2]); pk[7] = (short)f2bf(v1[3]);
    aF[s] = pk;
  }
#pragma unroll
  for (int off = 32; off; off >>= 1) xacc += __shfl_xor(xacc, off, 64);
  if (l == 0) atomicAdd(&sums[0], xacc);

  unsigned best_[16];
#pragma unroll
  for (int q = 0; q < 16; ++q) best_[q] = 0xFFFFFFFFu;

  f32x4v* encz = (f32x4v*)(encf + (size_t)row0 * KC);
  const f32x4v zero4 = {0.f, 0.f, 0.f, 0.f};

  // tile 0 resident: full drain, then barrier
  asm volatile("s_waitcnt vmcnt(0)" ::: "memory");
  __builtin_amdgcn_s_barrier();
  __builtin_amdgcn_sched_barrier(0);

  for (int kt = 0; kt < 32; ++kt) {
    const int buf = kt & 1;
    if (kt < 31) {  // prefetch next tile (8 gloads, issued first = oldest)
      const u16* src = WhTf + (size_t)(kt + 1) * 16384;
#pragma unroll
      for (int i = 0; i < 8; ++i)
        gload_lds16(src + i * 2048 + t * 8, &BsU[buf ^ 1][i * 2048 + t * 8]);
    }
    // stream one-hot zeros, non-temporal (4 stores, newest vmcnt entries)
#pragma unroll
    for (int j = 0; j < 4; ++j)
      __builtin_nontemporal_store(zero4, &encz[kt * 1024 + j * 256 + t]);

    const u16* bufp = &BsU[buf][l * 8];
    f32x16 acc_e = {}, acc_o = {};
#pragma unroll
    for (int ks = 0; ks < 32; ++ks) {
      short8 bv = *(const short8*)&bufp[ks * 512];
      if (ks & 1)
        acc_o = __builtin_amdgcn_mfma_f32_32x32x16_bf16(aF[ks], bv, acc_o, 0, 0, 0);
      else
        acc_e = __builtin_amdgcn_mfma_f32_32x32x16_bf16(aF[ks], bv, acc_e, 0, 0, 0);
    }
    float wn = wnorm[kt * 32 + r];
    unsigned col = (unsigned)(kt * 32 + r);
#pragma unroll
    for (int q = 0; q < 16; ++q) {
      float sc = fmaf(-2.0f, acc_e[q] + acc_o[q], wn);
      unsigned u_ = __float_as_uint(sc);
      unsigned key = (u_ & 0x80000000u) ? ~u_ : (u_ | 0x80000000u);
      best_[q] = min(best_[q], (key & 0xFFFFFC00u) | col);
    }
    // counted drain: gloads (oldest) done; <=4 NT stores may pipeline across
    asm volatile("s_waitcnt vmcnt(4)" ::: "memory");
    __builtin_amdgcn_s_barrier();
    __builtin_amdgcn_sched_barrier(0);
  }

  // per-row argmin across the 32 code-lanes
  double local = 0.0;
#pragma unroll
  for (int q = 0; q < 16; ++q) {
    unsigned pb = best_[q];
#pragma unroll
    for (int off = 16; off; off >>= 1)
      pb = min(pb, (unsigned)__shfl_xor((int)pb, off, 32));
    if (r == 0) {
      int rit = w * 32 + (q & 3) + 8 * (q >> 2) + 4 * h;
      int k = (int)(pb & 1023u);
      rowk[rit] = k;
      atomicAdd(&counts[k], 1);
      unsigned key = (pb & 0xFFFFFC00u) | 0x200u;  // midpoint reconstruction
      unsigned uu = (key & 0x80000000u) ? (key ^ 0x80000000u) : ~key;
      local += (double)__uint_as_float(uu);
    }
  }
  {
    double o32 = __shfl(local, 32, 64);
    if (l == 0) sdbl[w] = local + o32;
  }
  __syncthreads();  // full drain: zeros globally visible before 1.0 scatter
  if (t == 0) atomicAdd(&sums[1], sdbl[0] + sdbl[1] + sdbl[2] + sdbl[3]);

  // fused quantized gather-write: aligned float4 NT stores around the +1 base
  // quant[row][d] = out[row*512 + 1 + d]; aligned slots d = 3+4m, m=0..126
  for (int j = 0; j < 32; ++j) {
    int rit = w * 32 + j;
    int k = rowk[rit];
    const float* Wr = W + (size_t)k * DIM;
    size_t ob = (size_t)(row0 + rit) * DIM;
    {
      f32x4v cm = *(const f32x4v*)(Wr + 4 * l);
      f32x4v c1 = *(const f32x4v*)(Wr + 4 * l + 4);
      f32x4v sv = {cm[3], c1[0], c1[1], c1[2]};
      ntstore4(out + ob + 4 + 4 * l, sv);
    }
    if (l <= 62) {
      int m = l + 64;
      f32x4v dm = *(const f32x4v*)(Wr + 4 * m);
      f32x4v d1 = *(const f32x4v*)(Wr + 4 * m + 4);
      f32x4v sv = {dm[3], d1[0], d1[1], d1[2]};
      ntstore4(out + ob + 4 + 4 * m, sv);
    }
    if (l < 3) out[ob + 1 + l] = Wr[l];        // head d=0,1,2
    if (l == 3) out[ob + 512] = Wr[511];       // tail d=511
    if (l == 4) encf[(size_t)(row0 + rit) * KC + k] = 1.0f;  // one-hot
  }
}

// ---- finalize: loss + perplexity ------------------------------------------
__global__ __launch_bounds__(256) void finalize_kernel(
    const int* __restrict__ counts, const double* __restrict__ sums,
    float* __restrict__ out_loss, float* __restrict__ out_perp) {
  __shared__ float red[4];
  int t = threadIdx.x;
  float h = 0.f;
  for (int k = t; k < KC; k += 256) {
    float p = (float)counts[k] / (float)NROWS;
    h -= p * logf(p + 1e-10f);
  }
#pragma unroll
  for (int off = 32; off; off >>= 1) h += __shfl_xor(h, off, 64);
  if ((t & 63) == 0) red[t >> 6] = h;
  __syncthreads();
  if (t == 0) {
    float H = red[0] + red[1] + red[2] + red[3];
    *out_perp = expf(H);
    double m = (sums[0] + sums[1]) / (double)((long long)NROWS * DIM);
    *out_loss = (float)(1.25 * m);
  }
}

extern "C" void kernel_launch(void* const* d_in, const int* in_sizes, int n_in,
                              void* d_out, int out_size, void* d_ws, size_t ws_size,
                              hipStream_t stream) {
  const float* X = (const float*)d_in[0];
  const float* W = (const float*)d_in[1];
  float* out = (float*)d_out;
  char* ws = (char*)d_ws;

  float* out_loss = out;                     // [0]
  float* out_perp = out + 1 + NROWS * DIM;   // [33554433]
  float* encf     = out + 2 + NROWS * DIM;   // [33554434 ..), 16B-aligned

  short8* WhT8   = (short8*)ws;                        // 1 MB
  float*  wnorm  = (float*)(ws + (1040u << 10));       // 4 KB
  int*    counts = (int*)(ws + (1040u << 10) + 4096);  // 4 KB
  double* sums   = (double*)(ws + (1040u << 10) + 8192); // [0]=sumX2 [1]=sumS

  wprep_kernel<<<KC / 4, 256, 0, stream>>>(W, WhT8, wnorm, counts, sums);
  mm_kernel<<<NROWS / 128, 256, 0, stream>>>(X, W, (const u16*)WhT8, wnorm,
                                             counts, sums, out, encf);
  finalize_kernel<<<1, 256, 0, stream>>>(counts, sums, out_loss, out_perp);
}